// Round 17
// baseline (303.456 us; speedup 1.0000x reference)
//
#include <hip/hip_runtime.h>
#include <hip/hip_bf16.h>

// MultiHeadCrossAttention: B=4, C=512, HEADS=4, HD=128, L=100
// f1 -> 500 support tokens/batch, f2 -> 7500 query tokens/batch.
// out1: [4,5,512,100], out2: [4,75,512,100] concatenated in d_out.

#define QSCL  (0.08838834764831845f * 1.4426950408889634f)   // SCALE * log2(e)
#define KSPL  8
#define NRB2  59                     // dir-2 row blocks of 128 (59*128 >= 7500)
#define NRB1  4                      // dir-1 row blocks of 128 (4*128 >= 500)

using bf16x8 = __attribute__((ext_vector_type(8))) short;
using f32x4  = __attribute__((ext_vector_type(4))) float;

__device__ inline ushort f2bf(float x) {
    union { float f; unsigned u; } v; v.f = x;
    unsigned r = v.u + 0x7fff + ((v.u >> 16) & 1);   // RNE
    return (ushort)(r >> 16);
}

__device__ inline void gll16(const ushort* g, ushort* l) {
    __builtin_amdgcn_global_load_lds(
        (const __attribute__((address_space(1))) void*)g,
        (__attribute__((address_space(3))) void*)l, 16, 0, 0);
}

// ---------------------------------------------------------------------------
// pre_kernel: blocks [0,1536) = weight fp32->bf16 (x6, pre-scaled);
//             blocks [1536,1556) = totok f1; [1556,1856) = totok f2.
// Block 0 also zeroes the 64 dir-1 tile counters (combine-in-attn).
// ---------------------------------------------------------------------------
struct PreArgs { const float* w[6]; float s[6]; const float* f1; const float* f2; };

__global__ __launch_bounds__(256) void pre_kernel(
    PreArgs pa, ushort* __restrict__ Wb,
    ushort* __restrict__ f1t, ushort* __restrict__ f2t,
    uint* __restrict__ TileCnt)
{
    __shared__ ushort Ts[100 * 136];
    const int t   = threadIdx.x;
    const int bid = blockIdx.x;

    if (bid < 1536) {
        if (bid == 0 && t < 64) TileCnt[t] = 0;
        const int wsel = bid >> 8;
        const float* src = pa.w[wsel];
        const float sc = pa.s[wsel];
        ushort* d = Wb + (size_t)wsel * 262144;
        const int idx = ((bid & 255) * 256 + t) * 4;
        const float4 v = *(const float4*)(src + idx);
        ushort4 o;
        o.x = f2bf(v.x * sc); o.y = f2bf(v.y * sc);
        o.z = f2bf(v.z * sc); o.w = f2bf(v.w * sc);
        *(ushort4*)(d + idx) = o;
        return;
    }

    const int bn = bid - 1536;
    const float* Xb;
    ushort* Yb;
    if (bn < 20) { Xb = pa.f1 + (size_t)bn * 51200;        Yb = f1t + (size_t)bn * 51200; }
    else         { Xb = pa.f2 + (size_t)(bn - 20) * 51200; Yb = f2t + (size_t)(bn - 20) * 51200; }

    for (int c0 = 0; c0 < 512; c0 += 128) {
        __syncthreads();
        #pragma unroll
        for (int i = 0; i < 50; ++i) {
            const int id = i * 256 + t;
            const int c = id / 100, l = id - c * 100;
            Ts[l * 136 + c] = f2bf(Xb[(size_t)(c0 + c) * 100 + l]);
        }
        __syncthreads();
        #pragma unroll
        for (int i = 0; i < 7; ++i) {
            const int id = i * 256 + t;
            if (id < 1600) {
                const int cg = id & 15, l = id >> 4;
                *(uint4*)(Yb + (size_t)l * 512 + c0 + cg * 8) =
                    *(const uint4*)&Ts[l * 136 + cg * 8];
            }
        }
    }
}

// ---------------------------------------------------------------------------
// gemm_nt multi-job dispatch: C[m][n] = sum_k A[m][k]*B[n][k] (+bias*bscale).
// K=512 fixed, lda=ldb=512. 128x128 tile, BK=64, 4 waves, global_load_lds
// staging with XOR-preswizzled source. T1 bijective XCD swizzle; per-job
// reuse-dim-fastest ordering (fastn) for L2 panel reuse.
// EPI 0: bf16 C row-major [Mrows][ldC]. baxis 1: bias/col; 0: /row.
// EPI 2: fp32 final out with [c][l] transpose scatter.
// ---------------------------------------------------------------------------
struct GemmJob {
    const ushort* A; const ushort* B;
    const float* bias; void* C;
    size_t sA, sB, sC;
    float bscale;
    int ldC, Mrows, Ncols, gx, gy, fastn, baxis, nblk;
};

struct GemmJobs { GemmJob j0, j1, j2, j3; int ntot; };

template<int EPI>
__global__ __launch_bounds__(256) void gemm_nt(GemmJobs J)
{
    __shared__ ushort smem[17408];          // 34.8 KB: staging 32KB / epi overlay
    ushort* As = smem;                       // [128][64]
    ushort* Bs = smem + 8192;                // [128][64]

    // ---- bijective XCD swizzle (m204) over merged grid ----
    const int ntot = J.ntot;
    const int q8 = ntot >> 3, r8 = ntot & 7;
    const int xcd = blockIdx.x & 7, ii = blockIdx.x >> 3;
    const int work = (xcd < r8 ? xcd * (q8 + 1)
                               : r8 * (q8 + 1) + (xcd - r8) * q8) + ii;

    // ---- job select (scalar if-chain; no runtime array indexing) ----
    GemmJob j; int id;
    {
        const int c0 = J.j0.nblk;
        const int c1 = c0 + J.j1.nblk;
        const int c2 = c1 + J.j2.nblk;
        if (work < c0)      { j = J.j0; id = work; }
        else if (work < c1) { j = J.j1; id = work - c0; }
        else if (work < c2) { j = J.j2; id = work - c1; }
        else                { j = J.j3; id = work - c2; }
    }

    const int fx = id % j.gx;
    const int rem = id / j.gx;
    const int fy = rem % j.gy;
    const int bz = rem / j.gy;
    const int m0 = (j.fastn ? fy : fx) * 128;
    const int n0 = (j.fastn ? fx : fy) * 128;

    const int t    = threadIdx.x;
    const int lane = t & 63;
    const int w    = t >> 6;
    const int mw   = (w >> 1) * 64;
    const int nw   = (w & 1) * 64;
    const int Mrows = j.Mrows, Ncols = j.Ncols, ldC = j.ldC;
    const ushort* Ab = j.A + (size_t)bz * j.sA;
    const ushort* Bb = j.B + (size_t)bz * j.sB;
    const float* bias = j.bias;

    f32x4 acc[4][4];
    #pragma unroll
    for (int i = 0; i < 4; ++i)
        #pragma unroll
        for (int jj = 0; jj < 4; ++jj) acc[i][jj] = (f32x4){0.f, 0.f, 0.f, 0.f};

    const int lr = lane >> 3;      // 0..7 row within 8-row group
    const int cb = lane & 7;       // 16B granule within row

    for (int k0 = 0; k0 < 512; k0 += 64) {
        if (k0) __syncthreads();
        #pragma unroll
        for (int i = 0; i < 4; ++i) {
            const int row = w * 32 + i * 8 + lr;
            const int ar = min(m0 + row, Mrows - 1);
            gll16(Ab + (size_t)ar * 512 + k0 + ((cb ^ (row & 7)) * 8),
                  As + (w * 32 + i * 8) * 64);
            const int br = min(n0 + row, Ncols - 1);
            gll16(Bb + (size_t)br * 512 + k0 + ((cb ^ (row & 7)) * 8),
                  Bs + (w * 32 + i * 8) * 64);
        }
        __syncthreads();
        #pragma unroll
        for (int ks = 0; ks < 2; ++ks) {
            bf16x8 af[4], bv[4];
            #pragma unroll
            for (int mf = 0; mf < 4; ++mf) {
                const int row = mw + mf * 16 + (lane & 15);
                af[mf] = *(const bf16x8*)((const char*)As + row * 128 +
                          ((ks * 64 + (lane >> 4) * 16) ^ ((row & 7) << 4)));
            }
            #pragma unroll
            for (int nf = 0; nf < 4; ++nf) {
                const int row = nw + nf * 16 + (lane & 15);
                bv[nf] = *(const bf16x8*)((const char*)Bs + row * 128 +
                          ((ks * 64 + (lane >> 4) * 16) ^ ((row & 7) << 4)));
            }
            #pragma unroll
            for (int mf = 0; mf < 4; ++mf)
                #pragma unroll
                for (int nf = 0; nf < 4; ++nf)
                    acc[mf][nf] = __builtin_amdgcn_mfma_f32_16x16x32_bf16(
                        af[mf], bv[nf], acc[mf][nf], 0, 0, 0);
        }
    }
    __syncthreads();

    if (EPI == 0) {
        float bcol[4];
        if (j.baxis == 1) {
            #pragma unroll
            for (int nf = 0; nf < 4; ++nf)
                bcol[nf] = bias[n0 + nw + nf * 16 + (lane & 15)] * j.bscale;
        }
        ushort* Ts = smem;   // [128][136]
        #pragma unroll
        for (int mf = 0; mf < 4; ++mf) {
            #pragma unroll
            for (int r = 0; r < 4; ++r) {
                const int row = mw + mf * 16 + (lane >> 4) * 4 + r;
                const float brow = (j.baxis == 0) ? bias[m0 + row] * j.bscale : 0.f;
                #pragma unroll
                for (int nf = 0; nf < 4; ++nf) {
                    const int col = nw + nf * 16 + (lane & 15);
                    const float v = acc[mf][nf][r] +
                                    ((j.baxis == 1) ? bcol[nf] : brow);
                    Ts[row * 136 + col] = f2bf(v);
                }
            }
        }
        __syncthreads();
        ushort* Cb = (ushort*)j.C + (size_t)bz * j.sC;
        #pragma unroll
        for (int i = 0; i < 8; ++i) {
            const int id2 = i * 256 + t;
            const int row = id2 >> 4, cg = id2 & 15;
            if (m0 + row < Mrows)
                *(uint4*)(Cb + (size_t)(m0 + row) * ldC + n0 + cg * 8) =
                    *(const uint4*)&Ts[row * 136 + cg * 8];
        }
    } else {
        // EPI 2: fp32 final out with [c][l] scatter (bias per row)
        float* Ts2 = (float*)smem;   // [64][132]
        float* Cb = (float*)j.C + (size_t)bz * j.sC;
        const int colL = t & 127;
        const int rb2 = t >> 7;
        const int tg = n0 + colL;
        int nIdx = 0, lIdx = 0;
        if (tg < Ncols) { nIdx = tg / 100; lIdx = tg - nIdx * 100; }
        #pragma unroll
        for (int h = 0; h < 2; ++h) {
            __syncthreads();
            if ((mw >> 6) == h) {
                #pragma unroll
                for (int mf = 0; mf < 4; ++mf) {
                    #pragma unroll
                    for (int r = 0; r < 4; ++r) {
                        const int rowl = mf * 16 + (lane >> 4) * 4 + r;
                        const float brow = bias[m0 + h * 64 + rowl];
                        #pragma unroll
                        for (int nf = 0; nf < 4; ++nf) {
                            const int col = nw + nf * 16 + (lane & 15);
                            Ts2[rowl * 132 + col] = acc[mf][nf][r] + brow;
                        }
                    }
                }
            }
            __syncthreads();
            if (tg < Ncols) {
                float* dst = Cb + (size_t)nIdx * 51200 + lIdx;
                #pragma unroll
                for (int i = 0; i < 32; ++i) {
                    const int rowl = i * 2 + rb2;
                    const int c = m0 + h * 64 + rowl;
                    dst[(size_t)c * 100] = Ts2[rowl * 132 + colL];
                }
            }
        }
    }
}

// ---------------------------------------------------------------------------
// MFMA flash attention, both directions in ONE dispatch. (r16 loop.)
// NEW: dir-1 split-K combine folded in as a last-arriver tail — after a
// dir-1 block stores its (acc,m,l) partial it does threadfence + atomicAdd
// on the tile counter; the 8th arriver combines the whole 128-row tile into
// A1 (overlaps dir-2 blocks; removes the separate combine dispatch).
// Counters zeroed by pre_kernel each call (deterministic; fixed sum order).
// ---------------------------------------------------------------------------
__global__ __launch_bounds__(256, 2) void attn_mfma_kernel(
    const ushort* __restrict__ Q2, const ushort* __restrict__ K1,
    const ushort* __restrict__ V1t, const ushort* __restrict__ V2t,
    ushort* __restrict__ A2, ushort* __restrict__ A1,
    float* __restrict__ PartO, float* __restrict__ Pml,
    uint* __restrict__ TileCnt)
{
    __shared__ ushort Ks[2 * 64 * 128];   // 32 KB dbuf; reused as O-transpose
    __shared__ ushort Vs[2 * 128 * 64];   // 32 KB dbuf, XOR-swizzled

    const int t    = threadIdx.x;
    const int lane = t & 63;
    const int w    = t >> 6;          // 0..3

    // ---- balanced XCD decode: 182 works/XCD, ii<64 -> dir-1 (long first) ----
    const int flat = blockIdx.x;
    const int xcd = flat & 7, ii = flat >> 3;       // ii in 0..181
    const bool dir2 = (ii >= 64);
    int rb, h, b, sp = 0;
    if (dir2) {
        const int w2 = xcd * 118 + (ii - 64);       // 0..943
        rb = w2 % NRB2;
        const int hb = w2 / NRB2;
        h = hb & 3; b = hb >> 2;
    } else {
        const int w1 = xcd * 64 + ii;               // 0..511
        rb = w1 & 3; sp = (w1 >> 2) & 7;
        const int hb = w1 >> 5;
        h = hb & 3; b = hb >> 2;
    }

    const int TR = dir2 ? 7500 : 500;
    const int TK = dir2 ? 500 : 7500;
    const int strideV = dir2 ? 512 : 7552;
    const ushort* R  = dir2 ? Q2 : K1;
    const ushort* Kt = dir2 ? K1 : Q2;
    const ushort* Vt = dir2 ? V1t : V2t;

    const int r0 = rb * 128;
    const int ho = h * 128;

    int kbeg = 0, kend = TK;
    if (!dir2) {
        kbeg = sp * 938;
        kend = kbeg + 938; if (kend > TK) kend = TK;
    }

    // ---- Q fragments direct from global (row-clamped at tail), 2 groups ----
    bf16x8 qa0[4], qa1[4];
    {
        const ushort* Rb = R + (size_t)b * TR * 512;
        const int q0 = min(r0 + w * 32 + (lane & 15), TR - 1);
        const int q1 = min(r0 + w * 32 + 16 + (lane & 15), TR - 1);
        const ushort* qp0 = Rb + (size_t)q0 * 512 + ho + (lane >> 4) * 8;
        const ushort* qp1 = Rb + (size_t)q1 * 512 + ho + (lane >> 4) * 8;
        #pragma unroll
        for (int s = 0; s < 4; ++s) {
            qa0[s] = *(const bf16x8*)(qp0 + s * 32);
            qa1[s] = *(const bf16x8*)(qp1 + s * 32);
        }
    }

    const ushort* Kb = Kt + (size_t)b * TK * 512;
    const ushort* Vb = Vt + ((size_t)b * 512 + ho) * strideV;

    // per-lane staging offsets (ushort units; XOR preswizzle on source)
    const int krow_i = lane >> 4;            // row within 4-row K granule
    const int kcol   = (lane & 15) * 8;      // 16B col within 256B row
    const int vrow_i = lane >> 3;            // row within 8-row V granule
    const int vcol   = (lane & 7) * 8;       // 16B col within 128B row
    const int gq     = lane >> 4;            // 0..3 lane group

    float m_run0 = -3.0e38f, l_run0 = 0.f;   // q-group 0 (base-2)
    float m_run1 = -3.0e38f, l_run1 = 0.f;   // q-group 1
    f32x4 acc0[8], acc1[8];
    #pragma unroll
    for (int g = 0; g < 8; ++g) {
        acc0[g] = (f32x4){0.f, 0.f, 0.f, 0.f};
        acc1[g] = (f32x4){0.f, 0.f, 0.f, 0.f};
    }

    // ---- prologue: stage K(kbeg)+V(kbeg) into buf 0 ----
    #pragma unroll
    for (int i = 0; i < 4; ++i) {
        const int kr = w * 16 + i * 4 + krow_i;
        gll16(Kb + (size_t)(kbeg + kr) * 512 + ho + (kcol ^ ((kr & 7) << 3)),
              Ks + (w * 16 + i * 4) * 128);
        const int vd = w * 32 + i * 8 + vrow_i;
        gll16(Vb + (size_t)vd * strideV + kbeg + (vcol ^ ((vd & 7) << 3)),
              Vs + (w * 32 + i * 8) * 64);
    }
    asm volatile("s_waitcnt vmcnt(0)" ::: "memory");
    __builtin_amdgcn_s_barrier();
    __builtin_amdgcn_sched_barrier(0);

    int c = 0;
    for (int kbase = kbeg; kbase < kend; kbase += 64, ++c) {
        const ushort* KsC = Ks + (c & 1) * 8192;
        const ushort* VsC = Vs + (c & 1) * 8192;
        ushort* KsN = Ks + ((c + 1) & 1) * 8192;
        ushort* VsN = Vs + ((c + 1) & 1) * 8192;

        // ---- prefetch next chunk into the other buffers (waited at chunk end)
        const int kn = kbase + 64;
        if (kn < kend) {
            #pragma unroll
            for (int i = 0; i < 4; ++i) {
                const int kr = w * 16 + i * 4 + krow_i;
                gll16(Kb + (size_t)(kn + kr) * 512 + ho + (kcol ^ ((kr & 7) << 3)),
                      KsN + (w * 16 + i * 4) * 128);
                const int vd = w * 32 + i * 8 + vrow_i;
                gll16(Vb + (size_t)vd * strideV + kn + (vcol ^ ((vd & 7) << 3)),
                      VsN + (w * 32 + i * 8) * 64);
            }
        }

        // ---- swapped QK^T, K frag reused for both q-groups ----
        f32x4 sf0[4], sf1[4];
        __builtin_amdgcn_s_setprio(1);
        #pragma unroll
        for (int f = 0; f < 4; ++f) {
            f32x4 s0 = (f32x4){0.f, 0.f, 0.f, 0.f};
            f32x4 s1 = (f32x4){0.f, 0.f, 0.f, 0.f};
            const int kr = f * 16 + (lane & 15);
            const int kb2 = kr * 256, sw = (kr & 7) << 4, g16 = gq * 16;
            #pragma unroll
            for (int s4 = 0; s4 < 4; ++s4) {
                bf16x8 kf = *(const bf16x8*)((const char*)KsC + kb2 + ((s4 * 64 + g16) ^ sw));
                s0 = __builtin_amdgcn_mfma_f32_16x16x32_bf16(kf, qa0[s4], s0, 0, 0, 0);
                s1 = __builtin_amdgcn_mfma_f32_16x16x32_bf16(kf, qa1[s4], s1, 0, 0, 0);
            }
            sf0[f] = s0; sf1[f] = s1;
        }
        __builtin_amdgcn_s_setprio(0);

        // ---- key mask (partial chunks only) ----
        if (kbase + 64 > kend) {
            #pragma unroll
            for (int f = 0; f < 4; ++f)
                #pragma unroll
                for (int r = 0; r < 4; ++r)
                    if (kbase + f * 16 + gq * 4 + r >= kend) {
                        sf0[f][r] = -3.0e38f; sf1[f][r] = -3.0e38f;
                    }
        }
        // ---- softmax, group 0 ----
        {
            float mx = sf0[0][0];
            #pragma unroll
            for (int f = 0; f < 4; ++f)
                #pragma unroll
                for (int r = 0; r < 4; ++r) mx = fmaxf(mx, sf0[f][r]);
            mx = fmaxf(mx, __shfl_xor(mx, 16));
            mx = fmaxf(mx, __shfl_xor(mx, 32));
            if (__any(mx > m_run0 + 11.0f)) {
                const float mn = fmaxf(m_run0, mx);
                const float sc = __builtin_amdgcn_exp2f(m_run0 - mn);
                m_run0 = mn; l_run0 *= sc;
                float scal4[4];
                #pragma unroll
                for (int r = 0; r < 4; ++r)
                    scal4[r] = __shfl(sc, (lane & 48) + gq * 4 + r);
                #pragma unroll
                for (int g = 0; g < 8; ++g)
                    #pragma unroll
                    for (int r = 0; r < 4; ++r) acc0[g][r] *= scal4[r];
            }
            float rs = 0.f;
            #pragma unroll
            for (int f = 0; f < 4; ++f)
                #pragma unroll
                for (int r = 0; r < 4; ++r) {
                    const float p = __builtin_amdgcn_exp2f(sf0[f][r] - m_run0);
                    sf0[f][r] = p; rs += p;
                }
            rs += __shfl_xor(rs, 16);
            rs += __shfl_xor(rs, 32);
            l_run0 += rs;
        }
        // ---- softmax, group 1 ----
        {
            float mx = sf1[0][0];
            #pragma unroll
            for (int f = 0; f < 4; ++f)
                #pragma unroll
                for (int r = 0; r < 4; ++r) mx = fmaxf(mx, sf1[f][r]);
            mx = fmaxf(mx, __shfl_xor(mx, 16));
            mx = fmaxf(mx, __shfl_xor(mx, 32));
            if (__any(mx > m_run1 + 11.0f)) {
                const float mn = fmaxf(m_run1, mx);
                const float sc = __builtin_amdgcn_exp2f(m_run1 - mn);
                m_run1 = mn; l_run1 *= sc;
                float scal4[4];
                #pragma unroll
                for (int r = 0; r < 4; ++r)
                    scal4[r] = __shfl(sc, (lane & 48) + gq * 4 + r);
                #pragma unroll
                for (int g = 0; g < 8; ++g)
                    #pragma unroll
                    for (int r = 0; r < 4; ++r) acc1[g][r] *= scal4[r];
            }
            float rs = 0.f;
            #pragma unroll
            for (int f = 0; f < 4; ++f)
                #pragma unroll
                for (int r = 0; r < 4; ++r) {
                    const float p = __builtin_amdgcn_exp2f(sf1[f][r] - m_run1);
                    sf1[f][r] = p; rs += p;
                }
            rs += __shfl_xor(rs, 16);
            rs += __shfl_xor(rs, 32);
            l_run1 += rs;
        }

        // ---- pack P to bf16 + redistribute, both groups ----
        union { uint u[4]; bf16x8 v; } pa00, pa01, pa10, pa11;
        {
            uint pk0[4][2], pk1[4][2];
            #pragma unroll
            for (int f = 0; f < 4; ++f) {
                asm("v_cvt_pk_bf16_f32 %0, %1, %2" : "=v"(pk0[f][0]) : "v"(sf0[f][0]), "v"(sf0[f][1]));
                asm("v_cvt_pk_bf16_f32 %0, %1, %2" : "=v"(pk0[f][1]) : "v"(sf0[f][2]), "v"(sf0[f][3]));
                asm("v_cvt_pk_bf16_f32 %0, %1, %2" : "=v"(pk1[f][0]) : "v"(sf1[f][0]), "v"(sf1[f][1]));
                asm("v_cvt_pk_bf16_f32 %0, %1, %2" : "=v"(pk1[f][1]) : "v"(sf1[f][2]), "v"(sf1[f][3]));
            }
            #pragma unroll
            for (int u = 0; u < 4; ++u) {
                const int srcl = (lane & 15) + ((lane & 16) << 1) + ((u >> 1) << 4);
                const uint a0 = (uint)__shfl((int)pk0[0][u & 1], srcl);
                const uint b0 = (uint)__shfl((int)pk0[1][u & 1], srcl);
                const uint a1 = (uint)__shfl((int)pk0[2][u & 1], srcl);
                const uint b1 = (uint)__shfl((int)pk0[3][u & 1], srcl);
                pa00.u[u] = (lane & 32) ? b0 : a0;
                pa01.u[u] = (lane & 32) ? b1 : a1;
                const uint c0 = (uint)__shfl((int)pk1[0][u & 1], srcl);
                const uint d0 = (uint)__shfl((int)pk1[1][u & 1], srcl);
                const uint c1 = (uint)__shfl((int)pk1[2][u & 1], srcl);
                const uint d1 = (uint)__shfl((int)pk1[3][u & 1], srcl);
                pa10.u[u] = (lane & 32) ? d0 : c0;
                pa11.u[u] = (lane & 32) ? d1 : c1;
            }
        }

        // ---- PV: O[32 q x 128 d] += P[32 x 64] * V[64 x 128]; V reused ----
        {
            const int g16 = gq * 16;
            __builtin_amdgcn_s_setprio(1);
            #pragma unroll
            for (int g = 0; g < 8; ++g) {
                const int dr = g * 16 + (lane & 15);
                const int vb = dr * 128, vsw = (dr & 7) << 4;
                bf16x8 v0 = *(const bf16x8*)((const char*)VsC + vb + ((g16) ^ vsw));
                bf16x8 v1 = *(const bf16x8*)((const char*)VsC + vb + ((64 + g16) ^ vsw));
                acc0[g] = __builtin_amdgcn_mfma_f32_16x16x32_bf16(pa00.v, v0, acc0[g], 0, 0, 0);
                acc0[g] = __builtin_amdgcn_mfma_f32_16x16x32_bf16(pa01.v, v1, acc0[g], 0, 0, 0);
                acc1[g] = __builtin_amdgcn_mfma_f32_16x16x32_bf16(pa10.v, v0, acc1[g], 0, 0, 0);
                acc1[g] = __builtin_amdgcn_mfma_f32_16x16x32_bf16(pa11.v, v1, acc1[g], 0, 0, 0);
            }
            __builtin_amdgcn_s_setprio(0);
        }

        // ---- single end-of-chunk sync: prefetch landed + all buf reads done
        asm volatile("s_waitcnt vmcnt(0)" ::: "memory");
        __builtin_amdgcn_s_barrier();
        __builtin_amdgcn_sched_barrier(0);
    }

    // ---- epilogue: rows = r0 + w*32 + qf*16 + gq*4 + r ----
    if (dir2) {
        float linv0[4], linv1[4];
        #pragma unroll
        for (int r = 0; r < 4; ++r) {
            linv0[r] = 1.f / __shfl(l_run0, (lane & 48) + gq * 4 + r);
            linv1[r] = 1.f / __shfl(l_run1, (lane & 48) + gq * 4 + r);
        }
        // transpose O tile through Ks (idle; loop-end barrier passed).
        char* Ts = (char*)Ks;   // [128] rows x 256B, swizzled
        #pragma unroll
        for (int r = 0; r < 4; ++r) {
            const int rl0 = w * 32 + (gq << 2) + r;
            const int rl1 = rl0 + 16;
            const int sw0 = (rl0 & 7) << 4, sw1 = (rl1 & 7) << 4;
            #pragma unroll
            for (int g = 0; g < 8; ++g) {
                const int cb2 = g * 32 + (lane & 15) * 2;
                *(ushort*)(Ts + rl0 * 256 + (cb2 ^ sw0)) = f2bf(acc0[g][r] * linv0[r]);
                *(ushort*)(Ts + rl1 * 256 + (cb2 ^ sw1)) = f2bf(acc1[g][r] * linv1[r]);
            }
        }
        __syncthreads();
        #pragma unroll
        for (int i = 0; i < 8; ++i) {
            const int id = i * 256 + t;
            const int row = id >> 4, cg = id & 15;
            const int grow = r0 + row;
            if (grow < TR)
                *(uint4*)(A2 + ((size_t)b * TR + grow) * 512 + ho + cg * 8) =
                    *(const uint4*)(Ts + row * 256 + ((cg * 16) ^ ((row & 7) << 4)));
        }
    } else {
        const int tidx = (b * 4 + h) * NRB1 + rb;        // 0..63
        const size_t tile = (size_t)tidx * KSPL + sp;
        float* Po = PartO + tile * (128 * 128);
        float* Pm = Pml + tile * 256;
        #pragma unroll
        for (int r = 0; r < 4; ++r) {
            const int row0 = w * 32 + (gq << 2) + r;
            float* pp0 = Po + row0 * 128 + (lane & 15);
            #pragma unroll
            for (int g = 0; g < 8; ++g) pp0[g * 16] = acc0[g][r];
            const int row1 = w * 32 + 16 + (gq << 2) + r;
            float* pp1 = Po + row1 * 128 + (lane & 15);
            #pragma unroll
            for (int g = 0; g < 8; ++g) pp1[g * 16] = acc1[g][r];
        }
        if (lane < 16) {
            Pm[w * 32 + lane] = m_run0;
            Pm[w * 32 + 16 + lane] = m_run1;
            Pm[128 + w * 32 + lane] = l_run0;
            Pm[128 + w * 32 + 16 + lane] = l_run1;
        }

        // ---- last-arriver combine (device-scope fence + atomic, G16) ----
        __threadfence();
        if (t == 0) {
            const uint old = atomicAdd(&TileCnt[tidx], 1u);
            ((volatile uint*)Vs)[0] = old;
        }
        __syncthreads();
        const uint arriv = ((volatile uint*)Vs)[0];
        if (arriv == KSPL - 1) {
            __threadfence();   // acquire: all 8 partials visible
            const size_t tb2 = (size_t)tidx * KSPL;
            #pragma unroll
            for (int half = 0; half < 2; ++half) {
                const int row = half * 64 + (t >> 2);
                const int dq = (t & 3) * 32;
                float M = -3.0e38f;
                #pragma unroll
                for (int i = 0; i < KSPL; ++i)
                    M = fmaxf(M, Pml[(tb2 + i) * 256 + row]);
                float wt[KSPL], L = 0.f;
                #pragma unroll
                for (int i = 0; i < KSPL; ++i) {
                    const float wi = __builtin_amdgcn_exp2f(Pml[(tb2 + i) * 256 + row] - M);
                    wt[i] = wi;
                    L += wi * Pml[(tb2 + i) * 256 + 128 + row];
                }
                const int grow = r0 + row;
                if (grow < 500) {
                    const float invL = 1.f / L;
                    float o[32];
                    #pragma unroll
                    for (int jj = 0; jj < 32; ++jj) o[jj] = 0.f;
                    #pragma unroll
                    for (int i = 0; i < KSPL; ++i) {
                        const float* pp = PartO + (tb2 + i) * (128 * 128) + row * 128 + dq;
                        #pragma unroll
                        for (int jj = 0; jj < 32; jj += 4) {
                            const float4 v = *(const float4*)(pp + jj);
                            o[jj]   += wt[i] * v.x; o[jj+1] += wt[i] * v.y;
                            o[jj+2] += wt[i] * v.z; o[jj+3] += wt[i] * v.w;
                        }
                    }
                    ushort* Ab = A1 + ((size_t)b * 500 + grow) * 512 + ho + dq;
                    #pragma unroll
                    for (int jj = 0; jj < 32; jj += 4) {
                        ushort4 v;
                        v.x = f2bf(o[jj] * invL);   v.y = f2bf(o[jj+1] * invL);
                        v.z = f2bf(o[jj+2] * invL); v.w = f2bf(o[jj+3] * invL);
                        *(ushort4*)(Ab + jj) = v;
                    }
                }
            }
        }
    }
}

// ---------------------------------------------------------------------------
extern "C" void kernel_launch(void* const* d_in, const int* in_sizes, int n_in,
                              void* d_out, int out_size, void* d_ws, size_t ws_size,
                              hipStream_t stream) {
    const float* f1  = (const float*)d_in[0];
    const float* f2  = (const float*)d_in[1];
    const float* Wk1 = (const float*)d_in[2];
    const float* bk1 = (const float*)d_in[3];
    const float* Wv1 = (const float*)d_in[4];
    const float* bv1 = (const float*)d_in[5];
    const float* Wq2 = (const float*)d_in[6];
    const float* bq2 = (const float*)d_in[7];
    // d_in[8..9] = Wk2/bk2: unused by the reference outputs.
    const float* Wv2 = (const float*)d_in[10];
    const float* bv2 = (const float*)d_in[11];
    const float* Wo1 = (const float*)d_in[12];
    const float* bo1 = (const float*)d_in[13];
    const float* Wo2 = (const float*)d_in[14];
    const float* bo2 = (const float*)d_in[15];
    float* out = (float*)d_out;

    // ---- workspace layout (~169 MB) ----
    ushort* f1t = (ushort*)d_ws;                    // [4* 500][512]
    ushort* f2t = f1t + (size_t)1024000;            // [4*7500][512]
    ushort* Wb  = f2t + (size_t)15360000;           // [6][512][512]
    ushort* K1  = Wb  + (size_t)1572864;            // [4* 500][512]
    ushort* Q2  = K1  + (size_t)1024000;            // [4*7500][512] (pre-scaled)
    ushort* V1t = Q2  + (size_t)15360000;           // [4][512][512]
    ushort* V2t = V1t + (size_t)1048576;            // [4][512][7552]
    ushort* A1  = V2t + (size_t)15466496;           // [4* 500][512]
    ushort* A2  = A1  + (size_t)1024000;            // [4*7500][512]
    float* PartO = (float*)(A2 + (size_t)15360000); // 512 x [128][128]
    float* Pml   = PartO + (size_t)512*128*128;     // 512 x [256]
    uint* TileCnt = (uint*)(Pml + (size_t)512*256); // 64 counters

    const dim3 blk(256);

    const ushort* Wk1b = Wb;
    const ushort* Wv1b = Wb + 262144;
    const ushort* Wq2b = Wb + 2*262144;
    const ushort* Wv2b = Wb + 3*262144;
    const ushort* Wo1b = Wb + 4*262144;
    const ushort* Wo2b = Wb + 5*262144;

    // ---- pre-pass: weights (Wq2 pre-scaled) + both totoks + counter zero ----
    PreArgs pa;
    pa.w[0]=Wk1; pa.w[1]=Wv1; pa.w[2]=Wq2; pa.w[3]=Wv2; pa.w[4]=Wo1; pa.w[5]=Wo2;
    pa.s[0]=1.f; pa.s[1]=1.f; pa.s[2]=QSCL; pa.s[3]=1.f; pa.s[4]=1.f; pa.s[5]=1.f;
    pa.f1 = f1; pa.f2 = f2;
    pre_kernel<<<dim3(1856), blk, 0, stream>>>(pa, Wb, f1t, f2t, TileCnt);

    // ---- all four projections, ONE dispatch (2012 blocks, XCD-swizzled) ----
    GemmJob jK {f1t, Wk1b, bk1, K1, 0, 0, 0, 1.f, 512, 2000, 512,
                4, 16, 1, 1, 64};
    GemmJob jQ {f2t, Wq2b, bq2, Q2, 0, 0, 0, QSCL, 512, 30000, 512,
                4, 235, 1, 1, 940};
    GemmJob jV1{Wv1b, f1t, bv1, V1t, 0, (size_t)500*512, (size_t)512*512, 1.f,
                512, 512, 500, 4, 4, 0, 0, 64};
    GemmJob jV2{Wv2b, f2t, bv2, V2t, 0, (size_t)7500*512, (size_t)512*7552, 1.f,
                7552, 512, 7500, 4, 59, 0, 0, 944};
    GemmJobs JP{jK, jQ, jV1, jV2, 2012};
    gemm_nt<0><<<dim3(2012), blk, 0, stream>>>(JP);

    // ---- attention (combine folded in as last-arriver tail) ----
    attn_mfma_kernel<<<dim3(1456), dim3(256), 0, stream>>>(
        Q2, K1, V1t, V2t, A2, A1, PartO, Pml, TileCnt);

    // ---- o-projections (fused [c][l] transpose), one dispatch ----
    GemmJob jO1{Wo1b, A1, bo1, out, 0, (size_t)500*512, (size_t)5*51200, 1.f,
                0, 512, 500, 4, 4, 0, 0, 64};
    GemmJob jO2{Wo2b, A2, bo2, out + (size_t)1024000, 0, (size_t)7500*512,
                (size_t)75*51200, 1.f, 0, 512, 7500, 4, 59, 0, 0, 944};
    GemmJob jZ{};   // unused
    GemmJobs JO{jO1, jO2, jZ, jZ, 1008};
    gemm_nt<2><<<dim3(1008), blk, 0, stream>>>(JO);
}

// Round 18
// 232.043 us; speedup vs baseline: 1.3078x; 1.3078x over previous
//
#include <hip/hip_runtime.h>
#include <hip/hip_bf16.h>

// MultiHeadCrossAttention: B=4, C=512, HEADS=4, HD=128, L=100
// f1 -> 500 support tokens/batch, f2 -> 7500 query tokens/batch.
// out1: [4,5,512,100], out2: [4,75,512,100] concatenated in d_out.

#define QSCL  (0.08838834764831845f * 1.4426950408889634f)   // SCALE * log2(e)
#define KSPL  8
#define NRB2  59                     // dir-2 row blocks of 128 (59*128 >= 7500)
#define NRB1  4                      // dir-1 row blocks of 128 (4*128 >= 500)

using bf16x8 = __attribute__((ext_vector_type(8))) short;
using f32x4  = __attribute__((ext_vector_type(4))) float;

__device__ inline ushort f2bf(float x) {
    union { float f; unsigned u; } v; v.f = x;
    unsigned r = v.u + 0x7fff + ((v.u >> 16) & 1);   // RNE
    return (ushort)(r >> 16);
}

__device__ inline void gll16(const ushort* g, ushort* l) {
    __builtin_amdgcn_global_load_lds(
        (const __attribute__((address_space(1))) void*)g,
        (__attribute__((address_space(3))) void*)l, 16, 0, 0);
}

// ---------------------------------------------------------------------------
// pre_kernel: blocks [0,1536) = weight fp32->bf16 (x6, pre-scaled);
//             blocks [1536,1556) = totok f1; [1556,1856) = totok f2.
// ---------------------------------------------------------------------------
struct PreArgs { const float* w[6]; float s[6]; const float* f1; const float* f2; };

__global__ __launch_bounds__(256) void pre_kernel(
    PreArgs pa, ushort* __restrict__ Wb,
    ushort* __restrict__ f1t, ushort* __restrict__ f2t)
{
    __shared__ ushort Ts[100 * 136];
    const int t   = threadIdx.x;
    const int bid = blockIdx.x;

    if (bid < 1536) {
        const int wsel = bid >> 8;
        const float* src = pa.w[wsel];
        const float sc = pa.s[wsel];
        ushort* d = Wb + (size_t)wsel * 262144;
        const int idx = ((bid & 255) * 256 + t) * 4;
        const float4 v = *(const float4*)(src + idx);
        ushort4 o;
        o.x = f2bf(v.x * sc); o.y = f2bf(v.y * sc);
        o.z = f2bf(v.z * sc); o.w = f2bf(v.w * sc);
        *(ushort4*)(d + idx) = o;
        return;
    }

    const int bn = bid - 1536;
    const float* Xb;
    ushort* Yb;
    if (bn < 20) { Xb = pa.f1 + (size_t)bn * 51200;        Yb = f1t + (size_t)bn * 51200; }
    else         { Xb = pa.f2 + (size_t)(bn - 20) * 51200; Yb = f2t + (size_t)(bn - 20) * 51200; }

    for (int c0 = 0; c0 < 512; c0 += 128) {
        __syncthreads();
        #pragma unroll
        for (int i = 0; i < 50; ++i) {
            const int id = i * 256 + t;
            const int c = id / 100, l = id - c * 100;
            Ts[l * 136 + c] = f2bf(Xb[(size_t)(c0 + c) * 100 + l]);
        }
        __syncthreads();
        #pragma unroll
        for (int i = 0; i < 7; ++i) {
            const int id = i * 256 + t;
            if (id < 1600) {
                const int cg = id & 15, l = id >> 4;
                *(uint4*)(Yb + (size_t)l * 512 + c0 + cg * 8) =
                    *(const uint4*)&Ts[l * 136 + cg * 8];
            }
        }
    }
}

// ---------------------------------------------------------------------------
// gemm_nt multi-job dispatch: C[m][n] = sum_k A[m][k]*B[n][k] (+bias*bscale).
// K=512 fixed, lda=ldb=512. 128x128 tile, BK=64, 4 waves, global_load_lds
// staging with XOR-preswizzled source. T1 bijective XCD swizzle; per-job
// reuse-dim-fastest ordering (fastn) for L2 panel reuse.
// EPI 0: bf16 C row-major [Mrows][ldC]. baxis 1: bias/col; 0: /row.
// EPI 2: fp32 final out with [c][l] transpose scatter.
// ---------------------------------------------------------------------------
struct GemmJob {
    const ushort* A; const ushort* B;
    const float* bias; void* C;
    size_t sA, sB, sC;
    float bscale;
    int ldC, Mrows, Ncols, gx, gy, fastn, baxis, nblk;
};

struct GemmJobs { GemmJob j0, j1, j2, j3; int ntot; };

template<int EPI>
__global__ __launch_bounds__(256) void gemm_nt(GemmJobs J)
{
    __shared__ ushort smem[17408];          // 34.8 KB: staging 32KB / epi overlay
    ushort* As = smem;                       // [128][64]
    ushort* Bs = smem + 8192;                // [128][64]

    // ---- bijective XCD swizzle (m204) over merged grid ----
    const int ntot = J.ntot;
    const int q8 = ntot >> 3, r8 = ntot & 7;
    const int xcd = blockIdx.x & 7, ii = blockIdx.x >> 3;
    const int work = (xcd < r8 ? xcd * (q8 + 1)
                               : r8 * (q8 + 1) + (xcd - r8) * q8) + ii;

    // ---- job select (scalar if-chain; no runtime array indexing) ----
    GemmJob j; int id;
    {
        const int c0 = J.j0.nblk;
        const int c1 = c0 + J.j1.nblk;
        const int c2 = c1 + J.j2.nblk;
        if (work < c0)      { j = J.j0; id = work; }
        else if (work < c1) { j = J.j1; id = work - c0; }
        else if (work < c2) { j = J.j2; id = work - c1; }
        else                { j = J.j3; id = work - c2; }
    }

    const int fx = id % j.gx;
    const int rem = id / j.gx;
    const int fy = rem % j.gy;
    const int bz = rem / j.gy;
    const int m0 = (j.fastn ? fy : fx) * 128;
    const int n0 = (j.fastn ? fx : fy) * 128;

    const int t    = threadIdx.x;
    const int lane = t & 63;
    const int w    = t >> 6;
    const int mw   = (w >> 1) * 64;
    const int nw   = (w & 1) * 64;
    const int Mrows = j.Mrows, Ncols = j.Ncols, ldC = j.ldC;
    const ushort* Ab = j.A + (size_t)bz * j.sA;
    const ushort* Bb = j.B + (size_t)bz * j.sB;
    const float* bias = j.bias;

    f32x4 acc[4][4];
    #pragma unroll
    for (int i = 0; i < 4; ++i)
        #pragma unroll
        for (int jj = 0; jj < 4; ++jj) acc[i][jj] = (f32x4){0.f, 0.f, 0.f, 0.f};

    const int lr = lane >> 3;      // 0..7 row within 8-row group
    const int cb = lane & 7;       // 16B granule within row

    for (int k0 = 0; k0 < 512; k0 += 64) {
        if (k0) __syncthreads();
        #pragma unroll
        for (int i = 0; i < 4; ++i) {
            const int row = w * 32 + i * 8 + lr;
            const int ar = min(m0 + row, Mrows - 1);
            gll16(Ab + (size_t)ar * 512 + k0 + ((cb ^ (row & 7)) * 8),
                  As + (w * 32 + i * 8) * 64);
            const int br = min(n0 + row, Ncols - 1);
            gll16(Bb + (size_t)br * 512 + k0 + ((cb ^ (row & 7)) * 8),
                  Bs + (w * 32 + i * 8) * 64);
        }
        __syncthreads();
        #pragma unroll
        for (int ks = 0; ks < 2; ++ks) {
            bf16x8 af[4], bv[4];
            #pragma unroll
            for (int mf = 0; mf < 4; ++mf) {
                const int row = mw + mf * 16 + (lane & 15);
                af[mf] = *(const bf16x8*)((const char*)As + row * 128 +
                          ((ks * 64 + (lane >> 4) * 16) ^ ((row & 7) << 4)));
            }
            #pragma unroll
            for (int nf = 0; nf < 4; ++nf) {
                const int row = nw + nf * 16 + (lane & 15);
                bv[nf] = *(const bf16x8*)((const char*)Bs + row * 128 +
                          ((ks * 64 + (lane >> 4) * 16) ^ ((row & 7) << 4)));
            }
            #pragma unroll
            for (int mf = 0; mf < 4; ++mf)
                #pragma unroll
                for (int nf = 0; nf < 4; ++nf)
                    acc[mf][nf] = __builtin_amdgcn_mfma_f32_16x16x32_bf16(
                        af[mf], bv[nf], acc[mf][nf], 0, 0, 0);
        }
    }
    __syncthreads();

    if (EPI == 0) {
        float bcol[4];
        if (j.baxis == 1) {
            #pragma unroll
            for (int nf = 0; nf < 4; ++nf)
                bcol[nf] = bias[n0 + nw + nf * 16 + (lane & 15)] * j.bscale;
        }
        ushort* Ts = smem;   // [128][136]
        #pragma unroll
        for (int mf = 0; mf < 4; ++mf) {
            #pragma unroll
            for (int r = 0; r < 4; ++r) {
                const int row = mw + mf * 16 + (lane >> 4) * 4 + r;
                const float brow = (j.baxis == 0) ? bias[m0 + row] * j.bscale : 0.f;
                #pragma unroll
                for (int nf = 0; nf < 4; ++nf) {
                    const int col = nw + nf * 16 + (lane & 15);
                    const float v = acc[mf][nf][r] +
                                    ((j.baxis == 1) ? bcol[nf] : brow);
                    Ts[row * 136 + col] = f2bf(v);
                }
            }
        }
        __syncthreads();
        ushort* Cb = (ushort*)j.C + (size_t)bz * j.sC;
        #pragma unroll
        for (int i = 0; i < 8; ++i) {
            const int id2 = i * 256 + t;
            const int row = id2 >> 4, cg = id2 & 15;
            if (m0 + row < Mrows)
                *(uint4*)(Cb + (size_t)(m0 + row) * ldC + n0 + cg * 8) =
                    *(const uint4*)&Ts[row * 136 + cg * 8];
        }
    } else {
        // EPI 2: fp32 final out with [c][l] scatter (bias per row)
        float* Ts2 = (float*)smem;   // [64][132]
        float* Cb = (float*)j.C + (size_t)bz * j.sC;
        const int colL = t & 127;
        const int rb2 = t >> 7;
        const int tg = n0 + colL;
        int nIdx = 0, lIdx = 0;
        if (tg < Ncols) { nIdx = tg / 100; lIdx = tg - nIdx * 100; }
        #pragma unroll
        for (int h = 0; h < 2; ++h) {
            __syncthreads();
            if ((mw >> 6) == h) {
                #pragma unroll
                for (int mf = 0; mf < 4; ++mf) {
                    #pragma unroll
                    for (int r = 0; r < 4; ++r) {
                        const int rowl = mf * 16 + (lane >> 4) * 4 + r;
                        const float brow = bias[m0 + h * 64 + rowl];
                        #pragma unroll
                        for (int nf = 0; nf < 4; ++nf) {
                            const int col = nw + nf * 16 + (lane & 15);
                            Ts2[rowl * 132 + col] = acc[mf][nf][r] + brow;
                        }
                    }
                }
            }
            __syncthreads();
            if (tg < Ncols) {
                float* dst = Cb + (size_t)nIdx * 51200 + lIdx;
                #pragma unroll
                for (int i = 0; i < 32; ++i) {
                    const int rowl = i * 2 + rb2;
                    const int c = m0 + h * 64 + rowl;
                    dst[(size_t)c * 100] = Ts2[rowl * 132 + colL];
                }
            }
        }
    }
}

// ---------------------------------------------------------------------------
// MFMA flash attention, both directions in ONE dispatch. (r14 best config.)
// BM=128 q-rows, 4 waves x 32 q-rows (2 x 16-row q-groups; K/V frags reused).
// FULL K+V double-buffer (64KB LDS), ONE barrier per chunk:
//   issue K(i+1)+V(i+1) into buf^1 -> QK^T(i) -> softmax -> PV(i) ->
//   vmcnt(0) + barrier -> flip.
// __launch_bounds__(256,2): ~100 VGPR + 64 AGPR, no spill.
// ---------------------------------------------------------------------------
__global__ __launch_bounds__(256, 2) void attn_mfma_kernel(
    const ushort* __restrict__ Q2, const ushort* __restrict__ K1,
    const ushort* __restrict__ V1t, const ushort* __restrict__ V2t,
    ushort* __restrict__ A2, float* __restrict__ PartO, float* __restrict__ Pml)
{
    __shared__ ushort Ks[2 * 64 * 128];   // 32 KB dbuf, rows 256B, XOR-swizzled
    __shared__ ushort Vs[2 * 128 * 64];   // 32 KB dbuf, d-rows 128B, XOR-swizzled

    const int t    = threadIdx.x;
    const int lane = t & 63;
    const int w    = t >> 6;          // 0..3

    // ---- balanced XCD decode: 182 works/XCD, ii<64 -> dir-1 (long first) ----
    const int flat = blockIdx.x;
    const int xcd = flat & 7, ii = flat >> 3;       // ii in 0..181
    const bool dir2 = (ii >= 64);
    int rb, h, b, sp = 0;
    if (dir2) {
        const int w2 = xcd * 118 + (ii - 64);       // 0..943
        rb = w2 % NRB2;
        const int hb = w2 / NRB2;
        h = hb & 3; b = hb >> 2;
    } else {
        const int w1 = xcd * 64 + ii;               // 0..511
        rb = w1 & 3; sp = (w1 >> 2) & 7;
        const int hb = w1 >> 5;
        h = hb & 3; b = hb >> 2;
    }

    const int TR = dir2 ? 7500 : 500;
    const int TK = dir2 ? 500 : 7500;
    const int strideV = dir2 ? 512 : 7552;
    const ushort* R  = dir2 ? Q2 : K1;
    const ushort* Kt = dir2 ? K1 : Q2;
    const ushort* Vt = dir2 ? V1t : V2t;

    const int r0 = rb * 128;
    const int ho = h * 128;

    int kbeg = 0, kend = TK;
    if (!dir2) {
        kbeg = sp * 938;
        kend = kbeg + 938; if (kend > TK) kend = TK;
    }

    // ---- Q fragments direct from global (row-clamped at tail), 2 groups ----
    bf16x8 qa0[4], qa1[4];
    {
        const ushort* Rb = R + (size_t)b * TR * 512;
        const int q0 = min(r0 + w * 32 + (lane & 15), TR - 1);
        const int q1 = min(r0 + w * 32 + 16 + (lane & 15), TR - 1);
        const ushort* qp0 = Rb + (size_t)q0 * 512 + ho + (lane >> 4) * 8;
        const ushort* qp1 = Rb + (size_t)q1 * 512 + ho + (lane >> 4) * 8;
        #pragma unroll
        for (int s = 0; s < 4; ++s) {
            qa0[s] = *(const bf16x8*)(qp0 + s * 32);
            qa1[s] = *(const bf16x8*)(qp1 + s * 32);
        }
    }

    const ushort* Kb = Kt + (size_t)b * TK * 512;
    const ushort* Vb = Vt + ((size_t)b * 512 + ho) * strideV;

    // per-lane staging offsets (ushort units; XOR preswizzle on source)
    const int krow_i = lane >> 4;            // row within 4-row K granule
    const int kcol   = (lane & 15) * 8;      // 16B col within 256B row
    const int vrow_i = lane >> 3;            // row within 8-row V granule
    const int vcol   = (lane & 7) * 8;       // 16B col within 128B row
    const int gq     = lane >> 4;            // 0..3 lane group

    float m_run0 = -3.0e38f, l_run0 = 0.f;   // q-group 0 (base-2)
    float m_run1 = -3.0e38f, l_run1 = 0.f;   // q-group 1
    f32x4 acc0[8], acc1[8];
    #pragma unroll
    for (int g = 0; g < 8; ++g) {
        acc0[g] = (f32x4){0.f, 0.f, 0.f, 0.f};
        acc1[g] = (f32x4){0.f, 0.f, 0.f, 0.f};
    }

    // ---- prologue: stage K(kbeg)+V(kbeg) into buf 0 ----
    #pragma unroll
    for (int i = 0; i < 4; ++i) {
        const int kr = w * 16 + i * 4 + krow_i;
        gll16(Kb + (size_t)(kbeg + kr) * 512 + ho + (kcol ^ ((kr & 7) << 3)),
              Ks + (w * 16 + i * 4) * 128);
        const int vd = w * 32 + i * 8 + vrow_i;
        gll16(Vb + (size_t)vd * strideV + kbeg + (vcol ^ ((vd & 7) << 3)),
              Vs + (w * 32 + i * 8) * 64);
    }
    asm volatile("s_waitcnt vmcnt(0)" ::: "memory");
    __builtin_amdgcn_s_barrier();
    __builtin_amdgcn_sched_barrier(0);

    int c = 0;
    for (int kbase = kbeg; kbase < kend; kbase += 64, ++c) {
        const ushort* KsC = Ks + (c & 1) * 8192;
        const ushort* VsC = Vs + (c & 1) * 8192;
        ushort* KsN = Ks + ((c + 1) & 1) * 8192;
        ushort* VsN = Vs + ((c + 1) & 1) * 8192;

        // ---- prefetch next chunk into the other buffers (waited at chunk end)
        const int kn = kbase + 64;
        if (kn < kend) {
            #pragma unroll
            for (int i = 0; i < 4; ++i) {
                const int kr = w * 16 + i * 4 + krow_i;
                gll16(Kb + (size_t)(kn + kr) * 512 + ho + (kcol ^ ((kr & 7) << 3)),
                      KsN + (w * 16 + i * 4) * 128);
                const int vd = w * 32 + i * 8 + vrow_i;
                gll16(Vb + (size_t)vd * strideV + kn + (vcol ^ ((vd & 7) << 3)),
                      VsN + (w * 32 + i * 8) * 64);
            }
        }

        // ---- swapped QK^T, K frag reused for both q-groups ----
        // sf*[f][r] = S[key=f*16+4*gq+r][q = w*32 + qf*16 + (lane&15)]
        f32x4 sf0[4], sf1[4];
        __builtin_amdgcn_s_setprio(1);
        #pragma unroll
        for (int f = 0; f < 4; ++f) {
            f32x4 s0 = (f32x4){0.f, 0.f, 0.f, 0.f};
            f32x4 s1 = (f32x4){0.f, 0.f, 0.f, 0.f};
            const int kr = f * 16 + (lane & 15);
            const int kb2 = kr * 256, sw = (kr & 7) << 4, g16 = gq * 16;
            #pragma unroll
            for (int s4 = 0; s4 < 4; ++s4) {
                bf16x8 kf = *(const bf16x8*)((const char*)KsC + kb2 + ((s4 * 64 + g16) ^ sw));
                s0 = __builtin_amdgcn_mfma_f32_16x16x32_bf16(kf, qa0[s4], s0, 0, 0, 0);
                s1 = __builtin_amdgcn_mfma_f32_16x16x32_bf16(kf, qa1[s4], s1, 0, 0, 0);
            }
            sf0[f] = s0; sf1[f] = s1;
        }
        __builtin_amdgcn_s_setprio(0);

        // ---- key mask (partial chunks only) ----
        if (kbase + 64 > kend) {
            #pragma unroll
            for (int f = 0; f < 4; ++f)
                #pragma unroll
                for (int r = 0; r < 4; ++r)
                    if (kbase + f * 16 + gq * 4 + r >= kend) {
                        sf0[f][r] = -3.0e38f; sf1[f][r] = -3.0e38f;
                    }
        }
        // ---- softmax, group 0 ----
        {
            float mx = sf0[0][0];
            #pragma unroll
            for (int f = 0; f < 4; ++f)
                #pragma unroll
                for (int r = 0; r < 4; ++r) mx = fmaxf(mx, sf0[f][r]);
            mx = fmaxf(mx, __shfl_xor(mx, 16));
            mx = fmaxf(mx, __shfl_xor(mx, 32));
            if (__any(mx > m_run0 + 11.0f)) {
                const float mn = fmaxf(m_run0, mx);
                const float sc = __builtin_amdgcn_exp2f(m_run0 - mn);
                m_run0 = mn; l_run0 *= sc;
                float scal4[4];
                #pragma unroll
                for (int r = 0; r < 4; ++r)
                    scal4[r] = __shfl(sc, (lane & 48) + gq * 4 + r);
                #pragma unroll
                for (int g = 0; g < 8; ++g)
                    #pragma unroll
                    for (int r = 0; r < 4; ++r) acc0[g][r] *= scal4[r];
            }
            float rs = 0.f;
            #pragma unroll
            for (int f = 0; f < 4; ++f)
                #pragma unroll
                for (int r = 0; r < 4; ++r) {
                    const float p = __builtin_amdgcn_exp2f(sf0[f][r] - m_run0);
                    sf0[f][r] = p; rs += p;
                }
            rs += __shfl_xor(rs, 16);
            rs += __shfl_xor(rs, 32);
            l_run0 += rs;
        }
        // ---- softmax, group 1 ----
        {
            float mx = sf1[0][0];
            #pragma unroll
            for (int f = 0; f < 4; ++f)
                #pragma unroll
                for (int r = 0; r < 4; ++r) mx = fmaxf(mx, sf1[f][r]);
            mx = fmaxf(mx, __shfl_xor(mx, 16));
            mx = fmaxf(mx, __shfl_xor(mx, 32));
            if (__any(mx > m_run1 + 11.0f)) {
                const float mn = fmaxf(m_run1, mx);
                const float sc = __builtin_amdgcn_exp2f(m_run1 - mn);
                m_run1 = mn; l_run1 *= sc;
                float scal4[4];
                #pragma unroll
                for (int r = 0; r < 4; ++r)
                    scal4[r] = __shfl(sc, (lane & 48) + gq * 4 + r);
                #pragma unroll
                for (int g = 0; g < 8; ++g)
                    #pragma unroll
                    for (int r = 0; r < 4; ++r) acc1[g][r] *= scal4[r];
            }
            float rs = 0.f;
            #pragma unroll
            for (int f = 0; f < 4; ++f)
                #pragma unroll
                for (int r = 0; r < 4; ++r) {
                    const float p = __builtin_amdgcn_exp2f(sf1[f][r] - m_run1);
                    sf1[f][r] = p; rs += p;
                }
            rs += __shfl_xor(rs, 16);
            rs += __shfl_xor(rs, 32);
            l_run1 += rs;
        }

        // ---- pack P to bf16 + redistribute, both groups ----
        union { uint u[4]; bf16x8 v; } pa00, pa01, pa10, pa11;
        {
            uint pk0[4][2], pk1[4][2];
            #pragma unroll
            for (int f = 0; f < 4; ++f) {
                asm("v_cvt_pk_bf16_f32 %0, %1, %2" : "=v"(pk0[f][0]) : "v"(sf0[f][0]), "v"(sf0[f][1]));
                asm("v_cvt_pk_bf16_f32 %0, %1, %2" : "=v"(pk0[f][1]) : "v"(sf0[f][2]), "v"(sf0[f][3]));
                asm("v_cvt_pk_bf16_f32 %0, %1, %2" : "=v"(pk1[f][0]) : "v"(sf1[f][0]), "v"(sf1[f][1]));
                asm("v_cvt_pk_bf16_f32 %0, %1, %2" : "=v"(pk1[f][1]) : "v"(sf1[f][2]), "v"(sf1[f][3]));
            }
            #pragma unroll
            for (int u = 0; u < 4; ++u) {
                const int srcl = (lane & 15) + ((lane & 16) << 1) + ((u >> 1) << 4);
                const uint a0 = (uint)__shfl((int)pk0[0][u & 1], srcl);
                const uint b0 = (uint)__shfl((int)pk0[1][u & 1], srcl);
                const uint a1 = (uint)__shfl((int)pk0[2][u & 1], srcl);
                const uint b1 = (uint)__shfl((int)pk0[3][u & 1], srcl);
                pa00.u[u] = (lane & 32) ? b0 : a0;
                pa01.u[u] = (lane & 32) ? b1 : a1;
                const uint c0 = (uint)__shfl((int)pk1[0][u & 1], srcl);
                const uint d0 = (uint)__shfl((int)pk1[1][u & 1], srcl);
                const uint c1 = (uint)__shfl((int)pk1[2][u & 1], srcl);
                const uint d1 = (uint)__shfl((int)pk1[3][u & 1], srcl);
                pa10.u[u] = (lane & 32) ? d0 : c0;
                pa11.u[u] = (lane & 32) ? d1 : c1;
            }
        }

        // ---- PV: O[32 q x 128 d] += P[32 x 64] * V[64 x 128]; V reused ----
        {
            const int g16 = gq * 16;
            __builtin_amdgcn_s_setprio(1);
            #pragma unroll
            for (int g = 0; g < 8; ++g) {
                const int dr = g * 16 + (lane & 15);
                const int vb = dr * 128, vsw = (dr & 7) << 4;
                bf16x8 v0 = *(const bf16x8*)((const char*)VsC + vb + ((g16) ^ vsw));
                bf16x8 v1 = *(const bf16x8*)((const char*)VsC + vb + ((64 + g16) ^ vsw));
                acc0[g] = __builtin_amdgcn_mfma_f32_16x16x32_bf16(pa00.v, v0, acc0[g], 0, 0, 0);
                acc0[g] = __builtin_amdgcn_mfma_f32_16x16x32_bf16(pa01.v, v1, acc0[g], 0, 0, 0);
                acc1[g] = __builtin_amdgcn_mfma_f32_16x16x32_bf16(pa10.v, v0, acc1[g], 0, 0, 0);
                acc1[g] = __builtin_amdgcn_mfma_f32_16x16x32_bf16(pa11.v, v1, acc1[g], 0, 0, 0);
            }
            __builtin_amdgcn_s_setprio(0);
        }

        // ---- single end-of-chunk sync: prefetch landed + all buf reads done
        asm volatile("s_waitcnt vmcnt(0)" ::: "memory");
        __builtin_amdgcn_s_barrier();
        __builtin_amdgcn_sched_barrier(0);
    }

    // ---- epilogue: rows = r0 + w*32 + qf*16 + gq*4 + r ----
    if (dir2) {
        float linv0[4], linv1[4];
        #pragma unroll
        for (int r = 0; r < 4; ++r) {
            linv0[r] = 1.f / __shfl(l_run0, (lane & 48) + gq * 4 + r);
            linv1[r] = 1.f / __shfl(l_run1, (lane & 48) + gq * 4 + r);
        }
        #pragma unroll
        for (int r = 0; r < 4; ++r) {
            const int row0 = r0 + w * 32 + (gq << 2) + r;
            if (row0 < TR) {
                ushort* Ab2 = A2 + ((size_t)b * TR + row0) * 512 + ho + (lane & 15);
                #pragma unroll
                for (int g = 0; g < 8; ++g) Ab2[g * 16] = f2bf(acc0[g][r] * linv0[r]);
            }
            const int row1 = r0 + w * 32 + 16 + (gq << 2) + r;
            if (row1 < TR) {
                ushort* Ab2 = A2 + ((size_t)b * TR + row1) * 512 + ho + (lane & 15);
                #pragma unroll
                for (int g = 0; g < 8; ++g) Ab2[g * 16] = f2bf(acc1[g][r] * linv1[r]);
            }
        }
    } else {
        const size_t tile = (((size_t)b * 4 + h) * NRB1 + rb) * KSPL + sp;
        float* Po = PartO + tile * (128 * 128);
        float* Pm = Pml + tile * 256;
        #pragma unroll
        for (int r = 0; r < 4; ++r) {
            const int row0 = w * 32 + (gq << 2) + r;
            float* pp0 = Po + row0 * 128 + (lane & 15);
            #pragma unroll
            for (int g = 0; g < 8; ++g) pp0[g * 16] = acc0[g][r];
            const int row1 = w * 32 + 16 + (gq << 2) + r;
            float* pp1 = Po + row1 * 128 + (lane & 15);
            #pragma unroll
            for (int g = 0; g < 8; ++g) pp1[g * 16] = acc1[g][r];
        }
        if (lane < 16) {
            Pm[w * 32 + lane] = m_run0;
            Pm[w * 32 + 16 + lane] = m_run1;
            Pm[128 + w * 32 + lane] = l_run0;
            Pm[128 + w * 32 + 16 + lane] = l_run1;
        }
    }
}

// ---------------------------------------------------------------------------
// combine split-K partials (base-2 m): O = sum_i 2^{m_i-M} acc_i / sum ...
// grid (8,4,4): blockIdx.x = rb*2 + half (64-row halves of the 128-row tile).
// ---------------------------------------------------------------------------
__global__ __launch_bounds__(256) void attn_combine_kernel(
    const float* __restrict__ PartO, const float* __restrict__ Pml,
    ushort* __restrict__ Aout, int TR)
{
    const int t = threadIdx.x;
    const int rb = blockIdx.x >> 1, half = blockIdx.x & 1;
    const int h = blockIdx.y, b = blockIdx.z;
    const int row = half * 64 + (t >> 2);        // 0..127 within tile
    const int dq = (t & 3) * 32;
    const int r0 = rb * 128;
    const size_t tbase = (((size_t)b * 4 + h) * NRB1 + rb) * KSPL;

    float M = -3.0e38f;
    #pragma unroll
    for (int i = 0; i < KSPL; ++i)
        M = fmaxf(M, Pml[(tbase + i) * 256 + row]);
    float wt[KSPL], L = 0.f;
    #pragma unroll
    for (int i = 0; i < KSPL; ++i) {
        const float wi = __builtin_amdgcn_exp2f(Pml[(tbase + i) * 256 + row] - M);
        wt[i] = wi;
        L += wi * Pml[(tbase + i) * 256 + 128 + row];
    }
    if (r0 + row >= TR) return;
    const float invL = 1.f / L;

    float o[32];
    #pragma unroll
    for (int j = 0; j < 32; ++j) o[j] = 0.f;
    #pragma unroll
    for (int i = 0; i < KSPL; ++i) {
        const float* pp = PartO + (tbase + i) * (128 * 128) + row * 128 + dq;
        #pragma unroll
        for (int j = 0; j < 32; j += 4) {
            const float4 v = *(const float4*)(pp + j);
            o[j] += wt[i] * v.x; o[j+1] += wt[i] * v.y;
            o[j+2] += wt[i] * v.z; o[j+3] += wt[i] * v.w;
        }
    }
    ushort* Ab = Aout + ((size_t)b * TR + r0 + row) * 512 + h * 128 + dq;
    #pragma unroll
    for (int j = 0; j < 32; j += 4) {
        ushort4 v;
        v.x = f2bf(o[j] * invL); v.y = f2bf(o[j+1] * invL);
        v.z = f2bf(o[j+2] * invL); v.w = f2bf(o[j+3] * invL);
        *(ushort4*)(Ab + j) = v;
    }
}

// ---------------------------------------------------------------------------
extern "C" void kernel_launch(void* const* d_in, const int* in_sizes, int n_in,
                              void* d_out, int out_size, void* d_ws, size_t ws_size,
                              hipStream_t stream) {
    const float* f1  = (const float*)d_in[0];
    const float* f2  = (const float*)d_in[1];
    const float* Wk1 = (const float*)d_in[2];
    const float* bk1 = (const float*)d_in[3];
    const float* Wv1 = (const float*)d_in[4];
    const float* bv1 = (const float*)d_in[5];
    const float* Wq2 = (const float*)d_in[6];
    const float* bq2 = (const float*)d_in[7];
    // d_in[8..9] = Wk2/bk2: unused by the reference outputs.
    const float* Wv2 = (const float*)d_in[10];
    const float* bv2 = (const float*)d_in[11];
    const float* Wo1 = (const float*)d_in[12];
    const float* bo1 = (const float*)d_in[13];
    const float* Wo2 = (const float*)d_in[14];
    const float* bo2 = (const float*)d_in[15];
    float* out = (float*)d_out;

    // ---- workspace layout (~169 MB) ----
    ushort* f1t = (ushort*)d_ws;                    // [4* 500][512]
    ushort* f2t = f1t + (size_t)1024000;            // [4*7500][512]
    ushort* Wb  = f2t + (size_t)15360000;           // [6][512][512]
    ushort* K1  = Wb  + (size_t)1572864;            // [4* 500][512]
    ushort* Q2  = K1  + (size_t)1024000;            // [4*7500][512] (pre-scaled)
    ushort* V1t = Q2  + (size_t)15360000;           // [4][512][512]
    ushort* V2t = V1t + (size_t)1048576;            // [4][512][7552]
    ushort* A1  = V2t + (size_t)15466496;           // [4* 500][512]
    ushort* A2  = A1  + (size_t)1024000;            // [4*7500][512]
    float* PartO = (float*)(A2 + (size_t)15360000); // 512 x [128][128]
    float* Pml   = PartO + (size_t)512*128*128;     // 512 x [256]

    const dim3 blk(256);

    const ushort* Wk1b = Wb;
    const ushort* Wv1b = Wb + 262144;
    const ushort* Wq2b = Wb + 2*262144;
    const ushort* Wv2b = Wb + 3*262144;
    const ushort* Wo1b = Wb + 4*262144;
    const ushort* Wo2b = Wb + 5*262144;

    // ---- pre-pass: weights (Wq2 pre-scaled) + both totoks, one dispatch ----
    PreArgs pa;
    pa.w[0]=Wk1; pa.w[1]=Wv1; pa.w[2]=Wq2; pa.w[3]=Wv2; pa.w[4]=Wo1; pa.w[5]=Wo2;
    pa.s[0]=1.f; pa.s[1]=1.f; pa.s[2]=QSCL; pa.s[3]=1.f; pa.s[4]=1.f; pa.s[5]=1.f;
    pa.f1 = f1; pa.f2 = f2;
    pre_kernel<<<dim3(1856), blk, 0, stream>>>(pa, Wb, f1t, f2t);

    // ---- all four projections, ONE dispatch (2012 blocks, XCD-swizzled) ----
    GemmJob jK {f1t, Wk1b, bk1, K1, 0, 0, 0, 1.f, 512, 2000, 512,
                4, 16, 1, 1, 64};
    GemmJob jQ {f2t, Wq2b, bq2, Q2, 0, 0, 0, QSCL, 512, 30000, 512,
                4, 235, 1, 1, 940};
    GemmJob jV1{Wv1b, f1t, bv1, V1t, 0, (size_t)500*512, (size_t)512*512, 1.f,
                512, 512, 500, 4, 4, 0, 0, 64};
    GemmJob jV2{Wv2b, f2t, bv2, V2t, 0, (size_t)7500*512, (size_t)512*7552, 1.f,
                7552, 512, 7500, 4, 59, 0, 0, 944};
    GemmJobs JP{jK, jQ, jV1, jV2, 2012};
    gemm_nt<0><<<dim3(2012), blk, 0, stream>>>(JP);

    // ---- attention, both directions in one dispatch (256-thread blocks) ----
    attn_mfma_kernel<<<dim3(1456), dim3(256), 0, stream>>>(
        Q2, K1, V1t, V2t, A2, PartO, Pml);
    attn_combine_kernel<<<dim3(8, 4, 4), blk, 0, stream>>>(PartO, Pml, A1, 500);

    // ---- o-projections (fused [c][l] transpose), one dispatch ----
    GemmJob jO1{Wo1b, A1, bo1, out, 0, (size_t)500*512, (size_t)5*51200, 1.f,
                0, 512, 500, 4, 4, 0, 0, 64};
    GemmJob jO2{Wo2b, A2, bo2, out + (size_t)1024000, 0, (size_t)7500*512,
                (size_t)75*51200, 1.f, 0, 512, 7500, 4, 59, 0, 0, 944};
    GemmJob jZ{};   // unused
    GemmJobs JO{jO1, jO2, jZ, jZ, 1008};
    gemm_nt<2><<<dim3(1008), blk, 0, stream>>>(JO);
}